// Round 21
// baseline (2764.861 us; speedup 1.0000x reference)
//
#include <hip/hip_runtime.h>

typedef _Float16 f16;
typedef _Float16 f16x8 __attribute__((ext_vector_type(8)));
typedef float f32x4 __attribute__((ext_vector_type(4)));

__device__ __forceinline__ f16x8 cvt8(f32x4 lo, f32x4 hi) {
    f16x8 h;
    h[0] = (f16)lo[0]; h[1] = (f16)lo[1]; h[2] = (f16)lo[2]; h[3] = (f16)lo[3];
    h[4] = (f16)hi[0]; h[5] = (f16)hi[1]; h[6] = (f16)hi[2]; h[7] = (f16)hi[3];
    return h;
}

__global__ __launch_bounds__(256)
void cvt_f32_f16(const float* __restrict__ in, f16* __restrict__ out, long long n) {
    long long i = ((long long)blockIdx.x * 256 + threadIdx.x) * 8;
    const long long stride = (long long)gridDim.x * 256 * 8;
    for (; i < n; i += stride) {
        f32x4 a = *(const f32x4*)(in + i);
        f32x4 b = *(const f32x4*)(in + i + 4);
        *(f16x8*)(out + i) = cvt8(a, b);
    }
}

// Interleave Wg/Wu rows 16-wise into Wgu [2M, HD] f16:
//   Wgu row R: (R&31)<16 -> Wg row (R>>5)*16+(R&15); else Wu row same.
// Makes the fused GEMM1 a SINGLE-B GEMM structurally identical to the
// measured-faster down-GEMM (0.86 vs 0.99 us/step, r17 data).
__global__ __launch_bounds__(256)
void cvt_interleave_f32_f16(const float* __restrict__ Wg,
                            const float* __restrict__ Wu,
                            f16* __restrict__ out, long long total) {
    long long i = ((long long)blockIdx.x * 256 + threadIdx.x) * 8;
    const long long stride = (long long)gridDim.x * 256 * 8;
    for (; i < total; i += stride) {
        const long long row = i >> 12;           // HD = 4096
        const int col = (int)(i & 4095);
        const long long srow = ((row >> 5) << 4) | (row & 15);
        const float* src = ((row & 16) ? Wu : Wg) + srow * 4096 + col;
        *(f16x8*)(out + i) = cvt8(*(const f32x4*)src, *(const f32x4*)(src + 4));
    }
}

__global__ void fill_sentinel_f32(float* __restrict__ out, long long n) {
    long long i = (long long)blockIdx.x * blockDim.x + threadIdx.x;
    long long stride = (long long)gridDim.x * blockDim.x;
    for (; i < n; i += stride) out[i] = 1.0f;
}

// Async global->LDS, 16B/lane. Pass the WAVE-UNIFORM LDS base; HW adds lane*16.
__device__ __forceinline__ void gload_lds16(const f16* g, f16* l) {
    __builtin_amdgcn_global_load_lds(
        (const __attribute__((address_space(1))) unsigned int*)(unsigned long long)g,
        (__attribute__((address_space(3))) unsigned int*)(unsigned int)(unsigned long long)l,
        16, 0, 0);
}

// ============================== fast path (all-f16) ==========================
// Single-B NT GEMM (champion r11/r18 skeleton, non-fused structure):
//   BM=256, BN=256, BK=32, 512 thr (8 waves 2Mx4N), wave 128x64, acc=128 VGPR.
//   3 LDS bufs (96 KB), depth-2 counted vmcnt(4): prologue stage(0),stage(1);
//   iter t: vmcnt(4) [stage(t) done, stage(t+1) in flight], s_barrier,
//   stage(t+2)->buf[(t+2)%3], compute(t). VMEM never drains mid-loop.
//   Rotation swizzle (0 conflicts measured r8-r13): LDS[r][blk] holds global
//   16B blk (blk - r/2)&3; frag read of k-blk hi at row r -> (hi + r/2)&3.
//   MFMA 16x16x32 f16; C/D col=lane&15, row=(lane>>4)*4+j (verified).
// EPI=0 (down): C = f32 out [rows, HD].
// EPI=3 (gate+up, INTERLEAVED B = Wgu): B-fragment ni even/odd = gate/up for
//   the SAME output cols -> epilogue silu(g)*u in-register -> f16 H at col
//   blockCol/2 + waveN*32 + (ni>>1)*16 + fr. No dual-acc, no 3rd LDS region,
//   no RMW — tests whether the r17-measured 15%/step FUSED deficit is
//   structural (predict GEMM1 0.99 -> ~0.87 us/step).
template<int EPI>
__global__ __launch_bounds__(512, 2)
void mlp_gemm16d(const f16* __restrict__ A, const f16* __restrict__ B0,
                 void* __restrict__ Cv, int K, int ldc,
                 int nRow, int nCol, int RG) {
    __shared__ __align__(16) f16 smA[3][256 * 32];
    __shared__ __align__(16) f16 smB0[3][256 * 32];

    // ---- block remap: supergroups of RG row-blocks, col-outer within ----
    const int lin   = blockIdx.x;
    const int perSg = RG * nCol;
    const int sg    = lin / perSg;
    const int rem   = lin - sg * perSg;
    int rgIn = nRow - sg * RG; if (rgIn > RG) rgIn = RG;
    const int colB = rem / rgIn;
    const int rowB = sg * RG + (rem - colB * rgIn);

    const long long blockRow = (long long)rowB * 256;
    const long long blockCol = (long long)colB * 256;

    const int tid  = threadIdx.x;
    const int w    = tid >> 6;      // 0..7
    const int lane = tid & 63;
    const int waveM = w >> 2;       // 0..1 -> 128 rows
    const int waveN = w & 3;        // 0..3 -> 64 B-rows

    // ---- staging: thread covers 16B chunk (dr=tid>>2, blk=tid&3);
    // pre-rotated global source block gblk = (blk - dr/2)&3 (m173 pattern);
    // +128-row issues keep gblk (128/2 == 0 mod 4).
    const int dr   = tid >> 2;
    const int dblk = tid & 3;
    const int gblk = (dblk - (dr >> 1)) & 3;
    const f16* gA0  = A  + (blockRow + dr) * (long long)K + gblk * 8;  // rows 0-127
    const f16* gA1  = gA0 + 128 * (long long)K;                        // rows 128-255
    const f16* gB0a = B0 + (blockCol + dr) * (long long)K + gblk * 8;
    const f16* gB0b = gB0a + 128 * (long long)K;
    const int wbase = w * 512;      // wave-uniform LDS base (elems)

    // ---- fragment read offsets (16x16x32: row=lane&15, k=(lane>>4)*8) ----
    const int fr = lane & 15;
    const int hi = lane >> 4;       // k-block 0..3
    int aOff[8], bOff[4];
#pragma unroll
    for (int i = 0; i < 8; ++i) {
        const int r = waveM * 128 + i * 16 + fr;
        aOff[i] = r * 32 + (((hi + (r >> 1)) & 3) << 3);
    }
#pragma unroll
    for (int n = 0; n < 4; ++n) {
        const int r = waveN * 64 + n * 16 + fr;
        bOff[n] = r * 32 + (((hi + (r >> 1)) & 3) << 3);
    }

    f32x4 acc0[8][4];
#pragma unroll
    for (int mi = 0; mi < 8; ++mi)
#pragma unroll
        for (int ni = 0; ni < 4; ++ni)
            acc0[mi][ni] = (f32x4){0.f, 0.f, 0.f, 0.f};

    auto stage = [&](int b) {   // exactly 4 VMEM instructions per call
        gload_lds16(gA0,  &smA[b][wbase]);           gA0  += 32;
        gload_lds16(gA1,  &smA[b][4096 + wbase]);    gA1  += 32;
        gload_lds16(gB0a, &smB0[b][wbase]);          gB0a += 32;
        gload_lds16(gB0b, &smB0[b][4096 + wbase]);   gB0b += 32;
    };

    auto compute = [&](int b) {
        f16x8 aF[8], bF[4];
#pragma unroll
        for (int i = 0; i < 8; ++i) aF[i] = *(const f16x8*)(&smA[b][aOff[i]]);
#pragma unroll
        for (int n = 0; n < 4; ++n) bF[n] = *(const f16x8*)(&smB0[b][bOff[n]]);
#pragma unroll
        for (int mi = 0; mi < 8; ++mi)
#pragma unroll
            for (int ni = 0; ni < 4; ++ni)
                acc0[mi][ni] = __builtin_amdgcn_mfma_f32_16x16x32_f16(
                    aF[mi], bF[ni], acc0[mi][ni], 0, 0, 0);
    };

    const int nk = K >> 5;          // K/32 steps (>= 2)
    stage(0);
    stage(1);
    int cur = 0;
    for (int t = 0; t < nk - 1; ++t) {
        // retire stage(t) (8 outstanding -> 4); stage(t+1) stays in flight
        asm volatile("s_waitcnt vmcnt(4)" ::: "memory");
        __builtin_amdgcn_s_barrier();       // stage(t) visible; prev reads done
        __builtin_amdgcn_sched_barrier(0);
        if (t + 2 < nk) {
            int nb = cur + 2; if (nb >= 3) nb -= 3;
            stage(nb);                      // covered by ~2 compute phases
        }
        compute(cur);
        cur = (cur == 2) ? 0 : cur + 1;
    }
    asm volatile("s_waitcnt vmcnt(0)" ::: "memory");
    __builtin_amdgcn_s_barrier();
    __builtin_amdgcn_sched_barrier(0);
    compute(cur);

    // ---- epilogue: C/D layout col=lane&15, row=(lane>>4)*4+j ----
    const long long orBase = blockRow + waveM * 128 + hi * 4;
    if constexpr (EPI == 0) {
        const long long ocBase = blockCol + waveN * 64 + fr;
#pragma unroll
        for (int mi = 0; mi < 8; ++mi)
#pragma unroll
            for (int ni = 0; ni < 4; ++ni)
#pragma unroll
                for (int j = 0; j < 4; ++j) {
                    const long long idx =
                        (orBase + mi * 16 + j) * (long long)ldc +
                        (ocBase + ni * 16);
                    ((float*)Cv)[idx] = acc0[mi][ni][j];
                }
    } else {
        // interleaved gate/up: ni even = gate, ni odd = up, same output col.
        // H col = blockCol/2 + waveN*32 + (ni>>1)*16 + fr.
        const long long ocBase = (blockCol >> 1) + waveN * 32 + fr;
#pragma unroll
        for (int mi = 0; mi < 8; ++mi)
#pragma unroll
            for (int pi = 0; pi < 2; ++pi)
#pragma unroll
                for (int j = 0; j < 4; ++j) {
                    float g = acc0[mi][2 * pi][j];
                    float u = acc0[mi][2 * pi + 1][j];
                    float v = (g / (1.f + __expf(-g))) * u;   // silu(g)*u
                    const long long idx =
                        (orBase + mi * 16 + j) * (long long)ldc +
                        (ocBase + pi * 16);
                    ((f16*)Cv)[idx] = (f16)v;
                }
    }
}

// ======================= fallback path (f32 operands) ========================
template<bool IS16>
__device__ __forceinline__ f16x8 load8(const char* p) {
    if constexpr (IS16) return *(const f16x8*)p;
    const float* f = (const float*)p;
    return cvt8(*(const f32x4*)f, *(const f32x4*)(f + 4));
}

template<bool FUSED, bool A16, bool B16>
__global__ __launch_bounds__(256)
void mlp_gemm(const void* __restrict__ Av, const void* __restrict__ B0v,
              const void* __restrict__ B1v, void* __restrict__ Cv,
              int K, int ldc, int nRow, int nCol, int RG) {
    __shared__ __align__(16) f16 smA[128 * 32];
    __shared__ __align__(16) f16 smB0[128 * 32];
    __shared__ __align__(16) f16 smB1[FUSED ? 128 * 32 : 8];

    const int lin   = blockIdx.x;
    const int perSg = RG * nCol;
    const int sg    = lin / perSg;
    const int rem   = lin - sg * perSg;
    int rgIn = nRow - sg * RG; if (rgIn > RG) rgIn = RG;
    const int colB = rem / rgIn;
    const int rowB = sg * RG + (rem - colB * rgIn);

    const long long blockRow = (long long)rowB * 128;
    const long long blockCol = (long long)colB * 128;

    const int tid  = threadIdx.x;
    const int w    = tid >> 6;
    const int lane = tid & 63;
    const int waveM = w >> 1;
    const int waveN = w & 1;

    const int r0 = tid >> 2;
    const int s0 = tid & 3;
    const int szA = A16 ? 2 : 4;
    const int szB = B16 ? 2 : 4;
    const char* gA0  = (const char*)Av  + ((blockRow + r0)      * (long long)K + s0 * 8) * szA;
    const char* gA1  = (const char*)Av  + ((blockRow + r0 + 64) * (long long)K + s0 * 8) * szA;
    const char* gB00 = (const char*)B0v + ((blockCol + r0)      * (long long)K + s0 * 8) * szB;
    const char* gB01 = (const char*)B0v + ((blockCol + r0 + 64) * (long long)K + s0 * 8) * szB;
    const char* gB10 = FUSED ? (const char*)B1v + ((blockCol + r0)      * (long long)K + s0 * 8) * szB : nullptr;
    const char* gB11 = FUSED ? (const char*)B1v + ((blockCol + r0 + 64) * (long long)K + s0 * 8) * szB : nullptr;

    const int off0 = tid * 8;
    const int off1 = off0 + 2048;

    const int fr = lane & 15;
    const int fk = (lane >> 4) * 8;
    int offA[4], offB[4];
#pragma unroll
    for (int i = 0; i < 4; ++i) {
        offA[i] = (waveM * 64 + i * 16 + fr) * 32 + fk;
        offB[i] = (waveN * 64 + i * 16 + fr) * 32 + fk;
    }

    f32x4 acc0[4][4];
    f32x4 acc1[4][4];
#pragma unroll
    for (int mi = 0; mi < 4; ++mi)
#pragma unroll
        for (int ni = 0; ni < 4; ++ni) {
            acc0[mi][ni] = (f32x4){0.f, 0.f, 0.f, 0.f};
            if constexpr (FUSED) acc1[mi][ni] = (f32x4){0.f, 0.f, 0.f, 0.f};
        }

    const int ksteps = K >> 5;
    for (int kt = 0; kt < ksteps; ++kt) {
        f16x8 vA0  = load8<A16>(gA0);
        f16x8 vA1  = load8<A16>(gA1);
        f16x8 vB00 = load8<B16>(gB00);
        f16x8 vB01 = load8<B16>(gB01);
        f16x8 vB10, vB11;
        if constexpr (FUSED) {
            vB10 = load8<B16>(gB10);
            vB11 = load8<B16>(gB11);
        }
        gA0 += 32 * szA; gA1 += 32 * szA;
        gB00 += 32 * szB; gB01 += 32 * szB;
        if constexpr (FUSED) { gB10 += 32 * szB; gB11 += 32 * szB; }

        __syncthreads();

        *(f16x8*)(smA  + off0) = vA0;
        *(f16x8*)(smA  + off1) = vA1;
        *(f16x8*)(smB0 + off0) = vB00;
        *(f16x8*)(smB0 + off1) = vB01;
        if constexpr (FUSED) {
            *(f16x8*)(smB1 + off0) = vB10;
            *(f16x8*)(smB1 + off1) = vB11;
        }

        __syncthreads();

        f16x8 aF[4], bF[4], b1F[4];
#pragma unroll
        for (int i = 0; i < 4; ++i) aF[i] = *(const f16x8*)(smA + offA[i]);
#pragma unroll
        for (int i = 0; i < 4; ++i) bF[i] = *(const f16x8*)(smB0 + offB[i]);
        if constexpr (FUSED) {
#pragma unroll
            for (int i = 0; i < 4; ++i) b1F[i] = *(const f16x8*)(smB1 + offB[i]);
        }

#pragma unroll
        for (int mi = 0; mi < 4; ++mi)
#pragma unroll
            for (int ni = 0; ni < 4; ++ni) {
                acc0[mi][ni] = __builtin_amdgcn_mfma_f32_16x16x32_f16(
                    aF[mi], bF[ni], acc0[mi][ni], 0, 0, 0);
                if constexpr (FUSED)
                    acc1[mi][ni] = __builtin_amdgcn_mfma_f32_16x16x32_f16(
                        aF[mi], b1F[ni], acc1[mi][ni], 0, 0, 0);
            }
    }

    const long long orBase = blockRow + waveM * 64 + ((lane >> 4) * 4);
    const long long ocBase = blockCol + waveN * 64 + fr;
#pragma unroll
    for (int mi = 0; mi < 4; ++mi)
#pragma unroll
        for (int ni = 0; ni < 4; ++ni)
#pragma unroll
            for (int j = 0; j < 4; ++j) {
                const long long idx =
                    (orBase + mi * 16 + j) * (long long)ldc + (ocBase + ni * 16);
                if constexpr (FUSED) {
                    float gv = acc0[mi][ni][j];
                    float uv = acc1[mi][ni][j];
                    float v = (gv / (1.f + __expf(-gv))) * uv;
                    ((f16*)Cv)[idx] = (f16)v;
                } else {
                    ((float*)Cv)[idx] = acc0[mi][ni][j];
                }
            }
}

extern "C" void kernel_launch(void* const* d_in, const int* in_sizes, int n_in,
                              void* d_out, int out_size, void* d_ws, size_t ws_size,
                              hipStream_t stream) {
    const float* x  = (const float*)d_in[0];   // [T, HD] f32 (fp16-exact)
    const float* Wg = (const float*)d_in[1];   // [M, HD] f32
    const float* Wu = (const float*)d_in[2];   // [M, HD] f32
    const float* Wd = (const float*)d_in[3];   // [HD, M] f32
    float* out = (float*)d_out;                // [T, HD] f32

    const int HD = 4096;
    const int T  = in_sizes[0] / HD;           // 8192
    const int M  = in_sizes[1] / HD;           // 14336

    const long long nW = (long long)M * HD;
    const long long nX = (long long)T * HD;
    const size_t wBytes = (size_t)nW * 2;      // 117.4 MB
    const size_t xBytes = (size_t)nX * 2;      // 67.1 MB
    const size_t hRow   = (size_t)M * 2;
    const size_t minH   = 256 * hRow;          // 7.34 MB (one 256-row chunk)

    // carve d_ws: [Wgu (2x interleaved)][Wd16][X16][H...]
    char* p = (char*)d_ws;
    size_t rem = ws_size;
    f16 *Wgu = nullptr, *Wd16 = nullptr, *X16 = nullptr;
    bool fast = false;
    if (rem >= 3 * wBytes + xBytes + minH) {
        Wgu  = (f16*)p; p += 2 * wBytes;
        Wd16 = (f16*)p; p += wBytes;
        X16  = (f16*)p; p += xBytes;
        rem -= 3 * wBytes + xBytes;
        fast = true;
    }
    f16* H = (f16*)p;

    if (fast) {
        long long maxRows = (long long)(rem / hRow);
        int chunk = (int)((maxRows / 256) * 256);
        if (chunk > T) chunk = T;

        cvt_interleave_f32_f16<<<2048, 256, 0, stream>>>(Wg, Wu, Wgu, 2 * nW);
        cvt_f32_f16<<<2048, 256, 0, stream>>>(Wd, Wd16, nW);
        cvt_f32_f16<<<2048, 256, 0, stream>>>(x, X16, nX);

        const int nColGU = (2 * M) / 256;   // 112
        const int nColD  = HD / 256;        // 16
        for (int t0 = 0; t0 < T; t0 += chunk) {
            int rows = (T - t0 < chunk) ? (T - t0) : chunk;
            int nRow = rows / 256;
            // GEMM1: x @ Wgu^T (interleaved) -> H = silu(gate)*up  [rows, M]
            mlp_gemm16d<3><<<dim3(nRow * nColGU), 512, 0, stream>>>(
                X16 + (size_t)t0 * HD, Wgu, H, HD, M, nRow, nColGU, nRow);
            // GEMM2: H @ Wd^T -> out [rows, HD] f32
            int RG = (nRow < 16) ? nRow : 16;
            mlp_gemm16d<0><<<dim3(nRow * nColD), 512, 0, stream>>>(
                H, Wd16, out + (size_t)t0 * HD, M, HD, nRow, nColD, RG);
        }
        return;
    }

    // ---------- fallback: f32 operands, reg-staged 128-tiles ----------
    long long maxRows = (long long)(ws_size / hRow);
    int chunk = (int)((maxRows / 128) * 128);
    if (chunk > T) chunk = T;
    if (chunk <= 0) {
        fill_sentinel_f32<<<1024, 256, 0, stream>>>(out, (long long)out_size);
        return;
    }
    f16* Hf = (f16*)d_ws;
    for (int t0 = 0; t0 < T; t0 += chunk) {
        int rows = (T - t0 < chunk) ? (T - t0) : chunk;
        int nRow = rows / 128;
        {
            int nCol = M / 128;
            mlp_gemm<true, false, false><<<dim3(nRow * nCol), 256, 0, stream>>>(
                x + (size_t)t0 * HD, Wg, Wu, Hf, HD, M, nRow, nCol, nRow);
        }
        {
            int nCol = HD / 128;
            int RG = (nRow < 32) ? nRow : 32;
            mlp_gemm<false, true, false><<<dim3(nRow * nCol), 256, 0, stream>>>(
                Hf, Wd, nullptr, out + (size_t)t0 * HD, M, HD, nRow, nCol, RG);
        }
    }
}

// Round 22
// 2755.841 us; speedup vs baseline: 1.0033x; 1.0033x over previous
//
#include <hip/hip_runtime.h>

typedef _Float16 f16;
typedef _Float16 f16x8 __attribute__((ext_vector_type(8)));
typedef float f32x4 __attribute__((ext_vector_type(4)));

__device__ __forceinline__ f16x8 cvt8(f32x4 lo, f32x4 hi) {
    f16x8 h;
    h[0] = (f16)lo[0]; h[1] = (f16)lo[1]; h[2] = (f16)lo[2]; h[3] = (f16)lo[3];
    h[4] = (f16)hi[0]; h[5] = (f16)hi[1]; h[6] = (f16)hi[2]; h[7] = (f16)hi[3];
    return h;
}

__global__ __launch_bounds__(256)
void cvt_f32_f16(const float* __restrict__ in, f16* __restrict__ out, long long n) {
    long long i = ((long long)blockIdx.x * 256 + threadIdx.x) * 8;
    const long long stride = (long long)gridDim.x * 256 * 8;
    for (; i < n; i += stride) {
        f32x4 a = *(const f32x4*)(in + i);
        f32x4 b = *(const f32x4*)(in + i + 4);
        *(f16x8*)(out + i) = cvt8(a, b);
    }
}

// Interleave Wg/Wu rows 16-wise into Wgu [2M, HD] f16:
//   Wgu row R: (R&31)<16 -> Wg row (R>>5)*16+(R&15); else Wu row same.
// Makes the fused GEMM1 a SINGLE-B GEMM structurally identical to the
// measured-faster down-GEMM (0.86 vs 0.99 us/step, r17 data).
__global__ __launch_bounds__(256)
void cvt_interleave_f32_f16(const float* __restrict__ Wg,
                            const float* __restrict__ Wu,
                            f16* __restrict__ out, long long total) {
    long long i = ((long long)blockIdx.x * 256 + threadIdx.x) * 8;
    const long long stride = (long long)gridDim.x * 256 * 8;
    for (; i < total; i += stride) {
        const long long row = i >> 12;           // HD = 4096
        const int col = (int)(i & 4095);
        const long long srow = ((row >> 5) << 4) | (row & 15);
        const float* src = ((row & 16) ? Wu : Wg) + srow * 4096 + col;
        *(f16x8*)(out + i) = cvt8(*(const f32x4*)src, *(const f32x4*)(src + 4));
    }
}

__global__ void fill_sentinel_f32(float* __restrict__ out, long long n) {
    long long i = (long long)blockIdx.x * blockDim.x + threadIdx.x;
    long long stride = (long long)gridDim.x * blockDim.x;
    for (; i < n; i += stride) out[i] = 1.0f;
}

// Async global->LDS, 16B/lane. Pass the WAVE-UNIFORM LDS base; HW adds lane*16.
__device__ __forceinline__ void gload_lds16(const f16* g, f16* l) {
    __builtin_amdgcn_global_load_lds(
        (const __attribute__((address_space(1))) unsigned int*)(unsigned long long)g,
        (__attribute__((address_space(3))) unsigned int*)(unsigned int)(unsigned long long)l,
        16, 0, 0);
}

// ============================== fast path (all-f16) ==========================
// Single-B NT GEMM (champion r11/r18 skeleton, non-fused structure):
//   BM=256, BN=256, BK=32, 512 thr (8 waves 2Mx4N), wave 128x64, acc=128 VGPR.
//   3 LDS bufs (96 KB), depth-2 counted vmcnt(4): prologue stage(0),stage(1);
//   iter t: vmcnt(4) [stage(t) done, stage(t+1) in flight], s_barrier,
//   stage(t+2)->buf[(t+2)%3], compute(t). VMEM never drains mid-loop.
//   Rotation swizzle (0 conflicts measured r8-r13): LDS[r][blk] holds global
//   16B blk (blk - r/2)&3; frag read of k-blk hi at row r -> (hi + r/2)&3.
//   MFMA 16x16x32 f16; C/D col=lane&15, row=(lane>>4)*4+j (verified).
// EPI=0 (down): C = f32 out [rows, HD].
// EPI=3 (gate+up, INTERLEAVED B = Wgu): B-fragment ni even/odd = gate/up for
//   the SAME output cols -> epilogue silu(g)*u in-register -> f16 H at col
//   blockCol/2 + waveN*32 + (ni>>1)*16 + fr. No dual-acc, no 3rd LDS region,
//   no RMW — tests whether the r17-measured 15%/step FUSED deficit is
//   structural (predict GEMM1 0.99 -> ~0.87 us/step).
template<int EPI>
__global__ __launch_bounds__(512, 2)
void mlp_gemm16d(const f16* __restrict__ A, const f16* __restrict__ B0,
                 void* __restrict__ Cv, int K, int ldc,
                 int nRow, int nCol, int RG) {
    __shared__ __align__(16) f16 smA[3][256 * 32];
    __shared__ __align__(16) f16 smB0[3][256 * 32];

    // ---- block remap: supergroups of RG row-blocks, col-outer within ----
    const int lin   = blockIdx.x;
    const int perSg = RG * nCol;
    const int sg    = lin / perSg;
    const int rem   = lin - sg * perSg;
    int rgIn = nRow - sg * RG; if (rgIn > RG) rgIn = RG;
    const int colB = rem / rgIn;
    const int rowB = sg * RG + (rem - colB * rgIn);

    const long long blockRow = (long long)rowB * 256;
    const long long blockCol = (long long)colB * 256;

    const int tid  = threadIdx.x;
    const int w    = tid >> 6;      // 0..7
    const int lane = tid & 63;
    const int waveM = w >> 2;       // 0..1 -> 128 rows
    const int waveN = w & 3;        // 0..3 -> 64 B-rows

    // ---- staging: thread covers 16B chunk (dr=tid>>2, blk=tid&3);
    // pre-rotated global source block gblk = (blk - dr/2)&3 (m173 pattern);
    // +128-row issues keep gblk (128/2 == 0 mod 4).
    const int dr   = tid >> 2;
    const int dblk = tid & 3;
    const int gblk = (dblk - (dr >> 1)) & 3;
    const f16* gA0  = A  + (blockRow + dr) * (long long)K + gblk * 8;  // rows 0-127
    const f16* gA1  = gA0 + 128 * (long long)K;                        // rows 128-255
    const f16* gB0a = B0 + (blockCol + dr) * (long long)K + gblk * 8;
    const f16* gB0b = gB0a + 128 * (long long)K;
    const int wbase = w * 512;      // wave-uniform LDS base (elems)

    // ---- fragment read offsets (16x16x32: row=lane&15, k=(lane>>4)*8) ----
    const int fr = lane & 15;
    const int hi = lane >> 4;       // k-block 0..3
    int aOff[8], bOff[4];
#pragma unroll
    for (int i = 0; i < 8; ++i) {
        const int r = waveM * 128 + i * 16 + fr;
        aOff[i] = r * 32 + (((hi + (r >> 1)) & 3) << 3);
    }
#pragma unroll
    for (int n = 0; n < 4; ++n) {
        const int r = waveN * 64 + n * 16 + fr;
        bOff[n] = r * 32 + (((hi + (r >> 1)) & 3) << 3);
    }

    f32x4 acc0[8][4];
#pragma unroll
    for (int mi = 0; mi < 8; ++mi)
#pragma unroll
        for (int ni = 0; ni < 4; ++ni)
            acc0[mi][ni] = (f32x4){0.f, 0.f, 0.f, 0.f};

    auto stage = [&](int b) {   // exactly 4 VMEM instructions per call
        gload_lds16(gA0,  &smA[b][wbase]);           gA0  += 32;
        gload_lds16(gA1,  &smA[b][4096 + wbase]);    gA1  += 32;
        gload_lds16(gB0a, &smB0[b][wbase]);          gB0a += 32;
        gload_lds16(gB0b, &smB0[b][4096 + wbase]);   gB0b += 32;
    };

    auto compute = [&](int b) {
        f16x8 aF[8], bF[4];
#pragma unroll
        for (int i = 0; i < 8; ++i) aF[i] = *(const f16x8*)(&smA[b][aOff[i]]);
#pragma unroll
        for (int n = 0; n < 4; ++n) bF[n] = *(const f16x8*)(&smB0[b][bOff[n]]);
#pragma unroll
        for (int mi = 0; mi < 8; ++mi)
#pragma unroll
            for (int ni = 0; ni < 4; ++ni)
                acc0[mi][ni] = __builtin_amdgcn_mfma_f32_16x16x32_f16(
                    aF[mi], bF[ni], acc0[mi][ni], 0, 0, 0);
    };

    const int nk = K >> 5;          // K/32 steps (>= 2)
    stage(0);
    stage(1);
    int cur = 0;
    for (int t = 0; t < nk - 1; ++t) {
        // retire stage(t) (8 outstanding -> 4); stage(t+1) stays in flight
        asm volatile("s_waitcnt vmcnt(4)" ::: "memory");
        __builtin_amdgcn_s_barrier();       // stage(t) visible; prev reads done
        __builtin_amdgcn_sched_barrier(0);
        if (t + 2 < nk) {
            int nb = cur + 2; if (nb >= 3) nb -= 3;
            stage(nb);                      // covered by ~2 compute phases
        }
        compute(cur);
        cur = (cur == 2) ? 0 : cur + 1;
    }
    asm volatile("s_waitcnt vmcnt(0)" ::: "memory");
    __builtin_amdgcn_s_barrier();
    __builtin_amdgcn_sched_barrier(0);
    compute(cur);

    // ---- epilogue: C/D layout col=lane&15, row=(lane>>4)*4+j ----
    const long long orBase = blockRow + waveM * 128 + hi * 4;
    if constexpr (EPI == 0) {
        const long long ocBase = blockCol + waveN * 64 + fr;
#pragma unroll
        for (int mi = 0; mi < 8; ++mi)
#pragma unroll
            for (int ni = 0; ni < 4; ++ni)
#pragma unroll
                for (int j = 0; j < 4; ++j) {
                    const long long idx =
                        (orBase + mi * 16 + j) * (long long)ldc +
                        (ocBase + ni * 16);
                    ((float*)Cv)[idx] = acc0[mi][ni][j];
                }
    } else {
        // interleaved gate/up: ni even = gate, ni odd = up, same output col.
        // H col = blockCol/2 + waveN*32 + (ni>>1)*16 + fr.
        const long long ocBase = (blockCol >> 1) + waveN * 32 + fr;
#pragma unroll
        for (int mi = 0; mi < 8; ++mi)
#pragma unroll
            for (int pi = 0; pi < 2; ++pi)
#pragma unroll
                for (int j = 0; j < 4; ++j) {
                    float g = acc0[mi][2 * pi][j];
                    float u = acc0[mi][2 * pi + 1][j];
                    float v = (g / (1.f + __expf(-g))) * u;   // silu(g)*u
                    const long long idx =
                        (orBase + mi * 16 + j) * (long long)ldc +
                        (ocBase + pi * 16);
                    ((f16*)Cv)[idx] = (f16)v;
                }
    }
}

// ======================= fallback path (f32 operands) ========================
template<bool IS16>
__device__ __forceinline__ f16x8 load8(const char* p) {
    if constexpr (IS16) return *(const f16x8*)p;
    const float* f = (const float*)p;
    return cvt8(*(const f32x4*)f, *(const f32x4*)(f + 4));
}

template<bool FUSED, bool A16, bool B16>
__global__ __launch_bounds__(256)
void mlp_gemm(const void* __restrict__ Av, const void* __restrict__ B0v,
              const void* __restrict__ B1v, void* __restrict__ Cv,
              int K, int ldc, int nRow, int nCol, int RG) {
    __shared__ __align__(16) f16 smA[128 * 32];
    __shared__ __align__(16) f16 smB0[128 * 32];
    __shared__ __align__(16) f16 smB1[FUSED ? 128 * 32 : 8];

    const int lin   = blockIdx.x;
    const int perSg = RG * nCol;
    const int sg    = lin / perSg;
    const int rem   = lin - sg * perSg;
    int rgIn = nRow - sg * RG; if (rgIn > RG) rgIn = RG;
    const int colB = rem / rgIn;
    const int rowB = sg * RG + (rem - colB * rgIn);

    const long long blockRow = (long long)rowB * 128;
    const long long blockCol = (long long)colB * 128;

    const int tid  = threadIdx.x;
    const int w    = tid >> 6;
    const int lane = tid & 63;
    const int waveM = w >> 1;
    const int waveN = w & 1;

    const int r0 = tid >> 2;
    const int s0 = tid & 3;
    const int szA = A16 ? 2 : 4;
    const int szB = B16 ? 2 : 4;
    const char* gA0  = (const char*)Av  + ((blockRow + r0)      * (long long)K + s0 * 8) * szA;
    const char* gA1  = (const char*)Av  + ((blockRow + r0 + 64) * (long long)K + s0 * 8) * szA;
    const char* gB00 = (const char*)B0v + ((blockCol + r0)      * (long long)K + s0 * 8) * szB;
    const char* gB01 = (const char*)B0v + ((blockCol + r0 + 64) * (long long)K + s0 * 8) * szB;
    const char* gB10 = FUSED ? (const char*)B1v + ((blockCol + r0)      * (long long)K + s0 * 8) * szB : nullptr;
    const char* gB11 = FUSED ? (const char*)B1v + ((blockCol + r0 + 64) * (long long)K + s0 * 8) * szB : nullptr;

    const int off0 = tid * 8;
    const int off1 = off0 + 2048;

    const int fr = lane & 15;
    const int fk = (lane >> 4) * 8;
    int offA[4], offB[4];
#pragma unroll
    for (int i = 0; i < 4; ++i) {
        offA[i] = (waveM * 64 + i * 16 + fr) * 32 + fk;
        offB[i] = (waveN * 64 + i * 16 + fr) * 32 + fk;
    }

    f32x4 acc0[4][4];
    f32x4 acc1[4][4];
#pragma unroll
    for (int mi = 0; mi < 4; ++mi)
#pragma unroll
        for (int ni = 0; ni < 4; ++ni) {
            acc0[mi][ni] = (f32x4){0.f, 0.f, 0.f, 0.f};
            if constexpr (FUSED) acc1[mi][ni] = (f32x4){0.f, 0.f, 0.f, 0.f};
        }

    const int ksteps = K >> 5;
    for (int kt = 0; kt < ksteps; ++kt) {
        f16x8 vA0  = load8<A16>(gA0);
        f16x8 vA1  = load8<A16>(gA1);
        f16x8 vB00 = load8<B16>(gB00);
        f16x8 vB01 = load8<B16>(gB01);
        f16x8 vB10, vB11;
        if constexpr (FUSED) {
            vB10 = load8<B16>(gB10);
            vB11 = load8<B16>(gB11);
        }
        gA0 += 32 * szA; gA1 += 32 * szA;
        gB00 += 32 * szB; gB01 += 32 * szB;
        if constexpr (FUSED) { gB10 += 32 * szB; gB11 += 32 * szB; }

        __syncthreads();

        *(f16x8*)(smA  + off0) = vA0;
        *(f16x8*)(smA  + off1) = vA1;
        *(f16x8*)(smB0 + off0) = vB00;
        *(f16x8*)(smB0 + off1) = vB01;
        if constexpr (FUSED) {
            *(f16x8*)(smB1 + off0) = vB10;
            *(f16x8*)(smB1 + off1) = vB11;
        }

        __syncthreads();

        f16x8 aF[4], bF[4], b1F[4];
#pragma unroll
        for (int i = 0; i < 4; ++i) aF[i] = *(const f16x8*)(smA + offA[i]);
#pragma unroll
        for (int i = 0; i < 4; ++i) bF[i] = *(const f16x8*)(smB0 + offB[i]);
        if constexpr (FUSED) {
#pragma unroll
            for (int i = 0; i < 4; ++i) b1F[i] = *(const f16x8*)(smB1 + offB[i]);
        }

#pragma unroll
        for (int mi = 0; mi < 4; ++mi)
#pragma unroll
            for (int ni = 0; ni < 4; ++ni) {
                acc0[mi][ni] = __builtin_amdgcn_mfma_f32_16x16x32_f16(
                    aF[mi], bF[ni], acc0[mi][ni], 0, 0, 0);
                if constexpr (FUSED)
                    acc1[mi][ni] = __builtin_amdgcn_mfma_f32_16x16x32_f16(
                        aF[mi], b1F[ni], acc1[mi][ni], 0, 0, 0);
            }
    }

    const long long orBase = blockRow + waveM * 64 + ((lane >> 4) * 4);
    const long long ocBase = blockCol + waveN * 64 + fr;
#pragma unroll
    for (int mi = 0; mi < 4; ++mi)
#pragma unroll
        for (int ni = 0; ni < 4; ++ni)
#pragma unroll
            for (int j = 0; j < 4; ++j) {
                const long long idx =
                    (orBase + mi * 16 + j) * (long long)ldc + (ocBase + ni * 16);
                if constexpr (FUSED) {
                    float gv = acc0[mi][ni][j];
                    float uv = acc1[mi][ni][j];
                    float v = (gv / (1.f + __expf(-gv))) * uv;
                    ((f16*)Cv)[idx] = (f16)v;
                } else {
                    ((float*)Cv)[idx] = acc0[mi][ni][j];
                }
            }
}

extern "C" void kernel_launch(void* const* d_in, const int* in_sizes, int n_in,
                              void* d_out, int out_size, void* d_ws, size_t ws_size,
                              hipStream_t stream) {
    const float* x  = (const float*)d_in[0];   // [T, HD] f32 (fp16-exact)
    const float* Wg = (const float*)d_in[1];   // [M, HD] f32
    const float* Wu = (const float*)d_in[2];   // [M, HD] f32
    const float* Wd = (const float*)d_in[3];   // [HD, M] f32
    float* out = (float*)d_out;                // [T, HD] f32

    const int HD = 4096;
    const int T  = in_sizes[0] / HD;           // 8192
    const int M  = in_sizes[1] / HD;           // 14336

    const long long nW = (long long)M * HD;
    const long long nX = (long long)T * HD;
    const size_t wBytes = (size_t)nW * 2;      // 117.4 MB
    const size_t xBytes = (size_t)nX * 2;      // 67.1 MB
    const size_t hRow   = (size_t)M * 2;
    const size_t minH   = 256 * hRow;          // 7.34 MB (one 256-row chunk)

    // carve d_ws: [Wgu (2x interleaved)][Wd16][X16][H...]
    char* p = (char*)d_ws;
    size_t rem = ws_size;
    f16 *Wgu = nullptr, *Wd16 = nullptr, *X16 = nullptr;
    bool fast = false;
    if (rem >= 3 * wBytes + xBytes + minH) {
        Wgu  = (f16*)p; p += 2 * wBytes;
        Wd16 = (f16*)p; p += wBytes;
        X16  = (f16*)p; p += xBytes;
        rem -= 3 * wBytes + xBytes;
        fast = true;
    }
    f16* H = (f16*)p;

    if (fast) {
        long long maxRows = (long long)(rem / hRow);
        int chunk = (int)((maxRows / 256) * 256);
        if (chunk > T) chunk = T;

        cvt_interleave_f32_f16<<<2048, 256, 0, stream>>>(Wg, Wu, Wgu, 2 * nW);
        cvt_f32_f16<<<2048, 256, 0, stream>>>(Wd, Wd16, nW);
        cvt_f32_f16<<<2048, 256, 0, stream>>>(x, X16, nX);

        const int nColGU = (2 * M) / 256;   // 112
        const int nColD  = HD / 256;        // 16
        for (int t0 = 0; t0 < T; t0 += chunk) {
            int rows = (T - t0 < chunk) ? (T - t0) : chunk;
            int nRow = rows / 256;
            // GEMM1: x @ Wgu^T (interleaved) -> H = silu(gate)*up  [rows, M]
            mlp_gemm16d<3><<<dim3(nRow * nColGU), 512, 0, stream>>>(
                X16 + (size_t)t0 * HD, Wgu, H, HD, M, nRow, nColGU, nRow);
            // GEMM2: H @ Wd^T -> out [rows, HD] f32
            int RG = (nRow < 16) ? nRow : 16;
            mlp_gemm16d<0><<<dim3(nRow * nColD), 512, 0, stream>>>(
                H, Wd16, out + (size_t)t0 * HD, M, HD, nRow, nColD, RG);
        }
        return;
    }

    // ---------- fallback: f32 operands, reg-staged 128-tiles ----------
    long long maxRows = (long long)(ws_size / hRow);
    int chunk = (int)((maxRows / 128) * 128);
    if (chunk > T) chunk = T;
    if (chunk <= 0) {
        fill_sentinel_f32<<<1024, 256, 0, stream>>>(out, (long long)out_size);
        return;
    }
    f16* Hf = (f16*)d_ws;
    for (int t0 = 0; t0 < T; t0 += chunk) {
        int rows = (T - t0 < chunk) ? (T - t0) : chunk;
        int nRow = rows / 128;
        {
            int nCol = M / 128;
            mlp_gemm<true, false, false><<<dim3(nRow * nCol), 256, 0, stream>>>(
                x + (size_t)t0 * HD, Wg, Wu, Hf, HD, M, nRow, nCol, nRow);
        }
        {
            int nCol = HD / 128;
            int RG = (nRow < 32) ? nRow : 32;
            mlp_gemm<false, true, false><<<dim3(nRow * nCol), 256, 0, stream>>>(
                Hf, Wd, nullptr, out + (size_t)t0 * HD, M, HD, nRow, nCol, RG);
        }
    }
}